// Round 8
// baseline (743.061 us; speedup 1.0000x reference)
//
#include <hip/hip_runtime.h>
#include <stdint.h>

typedef unsigned short u16;
typedef uint32_t u32;

typedef __bf16 bf16x8 __attribute__((ext_vector_type(8)));
typedef _Float16 f16x8 __attribute__((ext_vector_type(8)));
typedef float f32x4 __attribute__((ext_vector_type(4)));
typedef _Float16 h2v __attribute__((ext_vector_type(2)));

union B8 { uint4 q; u32 u[4]; bf16x8 v; };
union H8 { uint4 q; u32 u[4]; f16x8 v; };

__device__ __forceinline__ u16 f2bf(float f) {
  u32 u = __float_as_uint(f);
  u32 r = (u + 0x7fffu + ((u >> 16) & 1u)) >> 16;
  return (u16)r;
}
__device__ __forceinline__ u16 f2h(float f) {
  union { _Float16 h; u16 u; } v; v.h = (_Float16)f; return v.u;
}
__device__ __forceinline__ float dot2h(u32 a, u32 b, float c) {
  union U { u32 u; h2v v; } A, B; A.u = a; B.u = b;
  return __builtin_amdgcn_fdot2(A.v, B.v, c, false);
}
__device__ __forceinline__ float sigf(float x) { return 1.f / (1.f + __expf(-x)); }
__device__ __forceinline__ float tanhf_fast(float x) {
  x = fminf(fmaxf(x, -15.f), 15.f);
  float e = __expf(2.f * x);
  return (e - 1.f) / (e + 1.f);
}

// ---------------- prep: pack/convert all weights ----------------
__global__ __launch_bounds__(256) void prep_k(
    const float* rnn_w_hh, const float* dec_w_hh, const float* conv1_w,
    const float* conv2_w, const float* rnn_w_ih, const float* dec_w_ih,
    const float* fc_w, const float* emb, const int* y,
    u32* wT2e, u32* wT2d, u16* w1b, u16* w2b, u16* wihb, u16* dwihb,
    u16* fcwb, u16* adec)
{
  int e = blockIdx.x * 256 + threadIdx.x;
  const int S0 = 24576, S1 = 24576, S2 = 5120, S3 = 163840, S4 = 208896,
            S5 = 12288, S6 = 524288, S7 = 130048;
  if (e < S0) { int g = e >> 6, k2 = e & 63;   // row-major [g][64], f16 pairs
    wT2e[e] = (u32)f2h(rnn_w_hh[g*128 + 2*k2]) | ((u32)f2h(rnn_w_hh[g*128 + 2*k2 + 1]) << 16);
    return; }
  e -= S0;
  if (e < S1) { int g = e >> 6, k2 = e & 63;
    wT2d[e] = (u32)f2h(dec_w_hh[g*128 + 2*k2]) | ((u32)f2h(dec_w_hh[g*128 + 2*k2 + 1]) << 16);
    return; }
  e -= S1;
  if (e < S2) { int kh = e >> 10, c = (e >> 5) & 31, kw = e & 31;
    w1b[e] = f2bf(conv1_w[c*160 + kh*32 + kw]); return; }
  e -= S2;
  if (e < S3) { int kt = e >> 10, c = (e >> 5) & 31, kw = e & 31;
    int ic = kt / 5, kh = kt - ic * 5;
    w2b[e] = f2bf(conv2_w[((c*32 + ic)*5 + kh)*32 + kw]); return; }
  e -= S3;
  if (e < S4) { wihb[e] = f2bf(rnn_w_ih[e]); return; }
  e -= S4;
  if (e < S5) { dwihb[e] = f2bf(dec_w_ih[e]); return; }
  e -= S5;
  if (e < S6) { fcwb[e] = f2bf(fc_w[e]); return; }
  e -= S6;
  if (e < S7) { int m = e >> 5, k = e & 31;
    int b = m / 127, t = m - b * 127;
    adec[e] = f2bf(emb[y[b*128 + t]*32 + k]); return; }
}

// ---------------- conv1: (32,1,512,161) -> in1b (32,32,254,72pad) bf16, MFMA ----------------
__global__ __launch_bounds__(256) void conv1_k(const float* x, const u16* w1b,
                                               const float* c1b, u16* in1b)
{
  __shared__ __align__(16) u16 slab[35 * 162];
  __shared__ __align__(16) u16 wl[5120];
  int b = blockIdx.x >> 4;
  int oh0 = (blockIdx.x & 15) * 16;
  int ih0 = oh0 * 2;
  for (int e = threadIdx.x; e < 35 * 161; e += 256) {
    int r = e / 161, iw = e - r * 161;
    int ih = ih0 + r;
    float v = (ih < 512) ? x[(b*512 + ih)*161 + iw] : 0.f;
    slab[r*162 + iw] = f2bf(v);
  }
  for (int e = threadIdx.x; e < 5120; e += 256) wl[e] = w1b[e];
  __syncthreads();
  int lane = threadIdx.x & 63, wid = threadIdx.x >> 6;
  int lrow = lane & 15, lk = (lane >> 4) * 8;
  B8 bw[5][2];
  #pragma unroll
  for (int kt = 0; kt < 5; kt++)
    #pragma unroll
    for (int ct = 0; ct < 2; ct++)
      bw[kt][ct].q = *(const uint4*)&wl[(kt*32 + ct*16 + lrow)*32 + lk];
  float bias0 = c1b[lrow], bias1 = c1b[16 + lrow];
  for (int mt = wid; mt < 65; mt += 4) {
    int m = mt * 16 + lrow;
    int ohl = m / 65, ow = m - ohl * 65;
    int ro = ohl * 324 + ow * 2 + lk;
    f32x4 a0, a1;
    #pragma unroll
    for (int i = 0; i < 4; i++) { a0[i] = 0.f; a1[i] = 0.f; }
    #pragma unroll
    for (int kt = 0; kt < 5; kt++) {
      B8 af;
      const u32* p = (const u32*)&slab[ro + kt * 162];
      af.u[0] = p[0]; af.u[1] = p[1]; af.u[2] = p[2]; af.u[3] = p[3];
      a0 = __builtin_amdgcn_mfma_f32_16x16x32_bf16(af.v, bw[kt][0].v, a0, 0, 0, 0);
      a1 = __builtin_amdgcn_mfma_f32_16x16x32_bf16(af.v, bw[kt][1].v, a1, 0, 0, 0);
    }
    int rb = mt * 16 + (lane >> 4) * 4;
    #pragma unroll
    for (int i = 0; i < 4; i++) {
      int mr = rb + i;
      int ohl2 = mr / 65, ow2 = mr - ohl2 * 65;
      int oh = oh0 + ohl2;
      if (oh < 254) {
        float v0 = fmaxf(a0[i] + bias0, 0.f);
        float v1 = fmaxf(a1[i] + bias1, 0.f);
        in1b[((b*32 + lrow)*254 + oh)*72 + ow2] = f2bf(v0);
        in1b[((b*32 + 16 + lrow)*254 + oh)*72 + ow2] = f2bf(v1);
      }
    }
  }
}

// ---------------- conv2: in1b (32,32,254,72) -> h (32,125,544) bf16, MFMA ----------------
__global__ __launch_bounds__(256) void conv2_k(const u16* in1b, const u16* w2b,
                                               const float* c2b, u16* hbf)
{
  extern __shared__ char smem[];
  u16* slab = (u16*)smem;              // [32][19][72]  = 87552 B
  u16* wl = (u16*)(smem + 87552);      // [32][32][32]  = 65536 B
  int b = blockIdx.x >> 4;
  int oh0 = (blockIdx.x & 15) * 8;
  int ih0 = oh0 * 2;
  for (int q = threadIdx.x; q < 5472; q += 256) {
    int ic = q / 171;
    int rem = q - ic * 171;
    int r = rem / 9, j = rem - r * 9;
    int ih = ih0 + r;
    uint4 v = make_uint4(0u, 0u, 0u, 0u);
    if (ih < 254) v = *(const uint4*)&in1b[(((b*32 + ic)*254 + ih)*72) + j*8];
    *(uint4*)&slab[(ic*19 + r)*72 + j*8] = v;
  }
  int lane = threadIdx.x & 63, wid = threadIdx.x >> 6;
  int lrow = lane & 15, lk = (lane >> 4) * 8;
  int ohl_[3], ow_[3];
  #pragma unroll
  for (int q = 0; q < 3; q++) {
    int mt = (q == 2) ? 8 : (wid + q * 4);
    int m = mt * 16 + lrow;
    if (m > 135) m = 0;
    ohl_[q] = m / 17; ow_[q] = m - ohl_[q] * 17;
  }
  f32x4 acc[3][2];
  #pragma unroll
  for (int q = 0; q < 3; q++)
    #pragma unroll
    for (int ct = 0; ct < 2; ct++)
      #pragma unroll
      for (int i = 0; i < 4; i++) acc[q][ct][i] = 0.f;

  for (int ph = 0; ph < 5; ph++) {
    __syncthreads();
    {
      const uint4* s4 = (const uint4*)&w2b[ph * 32768];
      uint4* d4 = (uint4*)wl;
      for (int q = threadIdx.x; q < 4096; q += 256) d4[q] = s4[q];
    }
    __syncthreads();
    for (int ktl = 0; ktl < 32; ktl++) {
      int ktg = ph * 32 + ktl;
      int ic = ktg / 5, kh = ktg - ic * 5;
      B8 fb0, fb1;
      fb0.q = *(const uint4*)&wl[(ktl*32 + lrow)*32 + lk];
      fb1.q = *(const uint4*)&wl[(ktl*32 + 16 + lrow)*32 + lk];
      int base = (ic * 19 + kh) * 72 + lk;
      #pragma unroll
      for (int q = 0; q < 3; q++) {
        if (q == 2 && wid != 0) break;
        B8 af;
        const u32* p = (const u32*)&slab[base + ohl_[q] * 144 + ow_[q] * 2];
        af.u[0] = p[0]; af.u[1] = p[1]; af.u[2] = p[2]; af.u[3] = p[3];
        acc[q][0] = __builtin_amdgcn_mfma_f32_16x16x32_bf16(af.v, fb0.v, acc[q][0], 0, 0, 0);
        acc[q][1] = __builtin_amdgcn_mfma_f32_16x16x32_bf16(af.v, fb1.v, acc[q][1], 0, 0, 0);
      }
    }
  }
  #pragma unroll
  for (int q = 0; q < 3; q++) {
    if (q == 2 && wid != 0) break;
    int mt = (q == 2) ? 8 : (wid + q * 4);
    int rb = mt * 16 + (lane >> 4) * 4;
    #pragma unroll
    for (int ct = 0; ct < 2; ct++) {
      int c = ct * 16 + lrow;
      float bias = c2b[c];
      #pragma unroll
      for (int i = 0; i < 4; i++) {
        int mr = rb + i;
        if (mr < 136) {
          int ohl = mr / 17, ow = mr - ohl * 17;
          int oh = oh0 + ohl;
          if (oh < 125) {
            float v = fmaxf(acc[q][ct][i] + bias, 0.f);
            hbf[(b*125 + oh)*544 + ow*32 + c] = f2bf(v);
          }
        }
      }
    }
  }
}

// ---------------- generic bf16 MFMA GEMM: C = A(MxK) * B(NxK)^T + bias ----------------
__global__ __launch_bounds__(256) void gemm_k(const u16* A, const u16* Bw,
                                              const float* bias, float* C,
                                              int M, int N, int K)
{
  __shared__ __align__(16) u16 As[64 * 32];
  __shared__ __align__(16) u16 Bs[64 * 32];
  int m0 = blockIdx.x * 64, n0 = blockIdx.y * 64;
  int tid = threadIdx.x;
  int lane = tid & 63, wid = tid >> 6;
  int lrow = lane & 15, lk = (lane >> 4) * 8;
  int sr = tid >> 2, sc8 = (tid & 3) * 8;
  f32x4 acc[4];
  #pragma unroll
  for (int nt = 0; nt < 4; nt++)
    #pragma unroll
    for (int i = 0; i < 4; i++) acc[nt][i] = 0.f;
  int nkt = K >> 5;
  for (int kt = 0; kt < nkt; kt++) {
    __syncthreads();
    uint4 va = make_uint4(0u, 0u, 0u, 0u);
    int arow = m0 + sr;
    if (arow < M) va = *(const uint4*)&A[arow * K + kt * 32 + sc8];
    *(uint4*)&As[sr * 32 + sc8] = va;
    uint4 vb = *(const uint4*)&Bw[(n0 + sr) * K + kt * 32 + sc8];
    *(uint4*)&Bs[sr * 32 + sc8] = vb;
    __syncthreads();
    B8 af; af.q = *(const uint4*)&As[(wid * 16 + lrow) * 32 + lk];
    #pragma unroll
    for (int nt = 0; nt < 4; nt++) {
      B8 bb; bb.q = *(const uint4*)&Bs[(nt * 16 + lrow) * 32 + lk];
      acc[nt] = __builtin_amdgcn_mfma_f32_16x16x32_bf16(af.v, bb.v, acc[nt], 0, 0, 0);
    }
  }
  #pragma unroll
  for (int nt = 0; nt < 4; nt++) {
    int col = n0 + nt * 16 + lrow;
    float bv = bias[col];
    #pragma unroll
    for (int i = 0; i < 4; i++) {
      int row = m0 + wid * 16 + (lane >> 4) * 4 + i;
      if (row < M) C[row * N + col] = acc[nt][i] + bv;
    }
  }
}

// ---------------- encoder GRU scan: 4 blocks x 1024 thr, 8 batches, MFMA gates ----------------
__global__ __launch_bounds__(1024) __attribute__((amdgpu_waves_per_eu(4, 4)))
void enc_k(const u32* wT2, const float* xg, const float* bhh_g, u16* ehk, u16* eht)
{
  __shared__ __align__(16) u16 hT[16 * 136];    // rows 0-7 = batches (f16), padded pitch
  __shared__ __align__(16) float hgP[8 * 384];
  int tid = threadIdx.x, wave = tid >> 6, lane = tid & 63;
  H8 wf[3][4];
  if (wave < 8) {
    #pragma unroll
    for (int j = 0; j < 3; j++)
      #pragma unroll
      for (int kt = 0; kt < 4; kt++) {
        int n = wave * 48 + j * 16 + (lane & 15);
        wf[j][kt].q = *(const uint4*)(wT2 + (size_t)n * 64 + kt * 16 + (lane >> 4) * 4);
      }
  }
  for (int e = tid; e < 16 * 136; e += 1024) hT[e] = 0;
  int b = tid >> 7, u = tid & 127;
  int bg = blockIdx.x * 8 + b;
  float b0 = bhh_g[u], b1 = bhh_g[128 + u], b2 = bhh_g[256 + u];
  const float* xp = &xg[(size_t)bg * 125 * 384];
  float xr0 = xp[u], xr1 = xp[128 + u], xr2 = xp[256 + u];
  float hreg = 0.f;
  __syncthreads();
  for (int tt = 0; tt < 125; tt++) {
    if (wave < 8) {
      f32x4 a0, a1, a2;
      #pragma unroll
      for (int i = 0; i < 4; i++) { a0[i] = 0.f; a1[i] = 0.f; a2[i] = 0.f; }
      const u16* hrow = hT + (lane & 15) * 136 + (lane >> 4) * 8;
      #pragma unroll
      for (int kt = 0; kt < 4; kt++) {
        H8 af; af.q = *(const uint4*)(hrow + kt * 32);
        a0 = __builtin_amdgcn_mfma_f32_16x16x32_f16(af.v, wf[0][kt].v, a0, 0, 0, 0);
        a1 = __builtin_amdgcn_mfma_f32_16x16x32_f16(af.v, wf[1][kt].v, a1, 0, 0, 0);
        a2 = __builtin_amdgcn_mfma_f32_16x16x32_f16(af.v, wf[2][kt].v, a2, 0, 0, 0);
      }
      if (lane < 32) {
        int g = wave * 48 + (lane & 15);
        int rb = (lane >> 4) * 4;
        #pragma unroll
        for (int i = 0; i < 4; i++) {
          int row = rb + i;
          hgP[row * 384 + g]      = a0[i];
          hgP[row * 384 + g + 16] = a1[i];
          hgP[row * 384 + g + 32] = a2[i];
        }
      }
    }
    __syncthreads();
    {
      float r = sigf(xr0 + hgP[b * 384 + u] + b0);
      float z = sigf(xr1 + hgP[b * 384 + 128 + u] + b1);
      float n = tanhf_fast(xr2 + r * (hgP[b * 384 + 256 + u] + b2));
      hreg = (1.f - z) * n + z * hreg;
      u16 hv = f2h(hreg);
      hT[b * 136 + u] = hv;
      ehk[((size_t)(bg * 64 + (u >> 1)) * 125 + tt) * 2 + (u & 1)] = hv;
      eht[((size_t)(bg * 128 + u)) * 128 + tt] = hv;
      if (tt + 1 < 125) {
        const float* xq = &xg[((size_t)bg * 125 + tt + 1) * 384];
        xr0 = xq[u]; xr1 = xq[128 + u]; xr2 = xq[256 + u];
      }
    }
    __syncthreads();
  }
  {
    size_t rb = ((size_t)(bg * 128 + u)) * 128;
    eht[rb + 125] = 0; eht[rb + 126] = 0; eht[rb + 127] = 0;
  }
}

// ---------------- decoder GRU + attention: 16 blocks x 1024 thr, 2 batches ----------------
// LDS: elK[2][8064] u32 | hxT[16][136] u16 | hgP[2][384] f32 | hxA[2][128] u16
//    | hgX[2][128] f32 | hxP[2][128] f32 | scp[2][128] u16 | red[2][16] f32  = 75136 B
__global__ __launch_bounds__(1024) __attribute__((amdgpu_waves_per_eu(4, 4)))
void dec_k(const u32* wT2, const u32* ehk_g, const u32* eht_g, const float* xgd,
           const float* bhh_g, const float* h_init, u16* outb)
{
  extern __shared__ char sm[];
  u32* elK   = (u32*)sm;                      // + b*8064
  u16* hxT   = (u16*)(sm + 64512);
  float* hgP = (float*)(sm + 68864);
  u16* hxA   = (u16*)(sm + 71936);
  float* hgX = (float*)(sm + 72448);
  float* hxP = (float*)(sm + 73472);
  u16* scp   = (u16*)(sm + 74496);
  float* red = (float*)(sm + 75008);
  const u32* hxA4 = (const u32*)hxA;
  const u32* scp4 = (const u32*)scp;

  int tid = threadIdx.x, wave = tid >> 6, lane = tid & 63;
  int b = wave >> 3;                 // batch for P3/P4 (waves 0-7 -> b0, 8-15 -> b1)
  int wb = wave & 7;                 // wave-in-batch
  int l4 = lane & 15, q = lane >> 4; // 16-lane group + quarter
  int bg = blockIdx.x * 2 + b;
  int t = wb * 16 + l4;              // time index (P3)
  int u = wb * 16 + l4;              // unit index (P4)

  // W_hh B-fragments (waves 0-7 only; M rows 0,1 = the two batches)
  H8 wf[3][4];
  if (wave < 8) {
    #pragma unroll
    for (int j = 0; j < 3; j++)
      #pragma unroll
      for (int kt = 0; kt < 4; kt++) {
        int n = wave * 48 + j * 16 + l4;
        wf[j][kt].q = *(const uint4*)(wT2 + (size_t)n * 64 + kt * 16 + (lane >> 4) * 4);
      }
  }
  // context operand rows (registers, step-constant): row u, t-pair quarter q
  u32 rowr[16];
  {
    const uint4* rp = (const uint4*)(eht_g + ((size_t)(bg * 128 + u)) * 64 + q * 16);
    #pragma unroll
    for (int j = 0; j < 4; j++) {
      uint4 v = rp[j];
      rowr[4*j] = v.x; rowr[4*j+1] = v.y; rowr[4*j+2] = v.z; rowr[4*j+3] = v.w;
    }
  }
  // stage elK (k-major) with zero pad to 8064
  {
    int tb = tid & 511, bb = tid >> 9;
    const uint4* s4 = (const uint4*)(ehk_g + (size_t)(blockIdx.x * 2 + bb) * 8000);
    uint4* d4 = (uint4*)(elK + bb * 8064);
    for (int qq = tb; qq < 2016; qq += 512) {
      uint4 v = make_uint4(0u, 0u, 0u, 0u);
      if (qq < 2000) v = s4[qq];
      d4[qq] = v;
    }
  }
  // init hxT / hxA / hgX / hxP
  for (int e = tid; e < 16 * 136; e += 1024) {
    int row = e / 136, col = e - row * 136;
    hxT[e] = (row < 2 && col < 128) ? f2h(h_init[col]) : (u16)0;
  }
  float b0 = 0.f, b1 = 0.f, b2c = 0.f, xr0 = 0.f, xr1 = 0.f, xr2 = 0.f;
  int b2 = tid >> 7, u2 = tid & 127;   // P2 mapping (tid<256)
  if (tid < 256) {
    float hi = h_init[u2];
    hxA[b2 * 128 + u2] = f2h(hi);
    hgX[b2 * 128 + u2] = hi;
    hxP[b2 * 128 + u2] = hi;
    b0 = bhh_g[u2]; b1 = bhh_g[128 + u2]; b2c = bhh_g[256 + u2];
    int bg2 = blockIdx.x * 2 + b2;
    const float* xp = &xgd[(size_t)bg2 * 127 * 384];
    xr0 = xp[u2]; xr1 = xp[128 + u2]; xr2 = xp[256 + u2];
  }
  const u32* elK_b = elK + b * 8064;
  __syncthreads();

  for (int step = 0; step < 128; step++) {
    // ---- P1: GRU gates via MFMA (waves 0-7; M rows = 2 batches) ----
    if (step > 0 && wave < 8) {
      f32x4 a0, a1, a2;
      #pragma unroll
      for (int i = 0; i < 4; i++) { a0[i] = 0.f; a1[i] = 0.f; a2[i] = 0.f; }
      const u16* hrow = hxT + l4 * 136 + (lane >> 4) * 8;
      #pragma unroll
      for (int kt = 0; kt < 4; kt++) {
        H8 af; af.q = *(const uint4*)(hrow + kt * 32);
        a0 = __builtin_amdgcn_mfma_f32_16x16x32_f16(af.v, wf[0][kt].v, a0, 0, 0, 0);
        a1 = __builtin_amdgcn_mfma_f32_16x16x32_f16(af.v, wf[1][kt].v, a1, 0, 0, 0);
        a2 = __builtin_amdgcn_mfma_f32_16x16x32_f16(af.v, wf[2][kt].v, a2, 0, 0, 0);
      }
      if (lane < 16) {
        int g = wave * 48 + lane;
        hgP[g]            = a0[0]; hgP[384 + g]            = a0[1];
        hgP[g + 16]       = a1[0]; hgP[384 + g + 16]       = a1[1];
        hgP[g + 32]       = a2[0]; hgP[384 + g + 32]       = a2[1];
      }
    }
    __syncthreads();                                   // bar1
    // ---- P2: gate nonlinearity (tid<256) ----
    if (step > 0 && tid < 256) {
      float hprev = hxP[b2 * 128 + u2];
      float r = sigf(xr0 + hgP[b2 * 384 + u2] + b0);
      float z = sigf(xr1 + hgP[b2 * 384 + 128 + u2] + b1);
      float n = tanhf_fast(xr2 + r * (hgP[b2 * 384 + 256 + u2] + b2c));
      float hxg = (1.f - z) * n + z * hprev;
      hxA[b2 * 128 + u2] = f2h(hxg);
      hgX[b2 * 128 + u2] = hxg;
      if (step < 127) {
        int bg2 = blockIdx.x * 2 + b2;
        const float* xq = &xgd[((size_t)bg2 * 127 + step) * 384];
        xr0 = xq[u2]; xr1 = xq[128 + u2]; xr2 = xq[256 + u2];
      }
    }
    __syncthreads();                                   // bar2
    // ---- P3: scores (K-split 4 in-wave) + 16-wide window softmax ----
    {
      float s0 = 0.f, s1 = 0.f;
      #pragma unroll
      for (int jj = 0; jj < 4; jj++) {
        uint4 aw = *(const uint4*)(hxA4 + b * 64 + q * 16 + 4 * jj);
        int k2 = q * 16 + 4 * jj;
        s0 = dot2h(elK_b[(k2 + 0) * 125 + t], aw.x, s0);
        s1 = dot2h(elK_b[(k2 + 1) * 125 + t], aw.y, s1);
        s0 = dot2h(elK_b[(k2 + 2) * 125 + t], aw.z, s0);
        s1 = dot2h(elK_b[(k2 + 3) * 125 + t], aw.w, s1);
      }
      float s = s0 + s1;
      s += __shfl_xor(s, 16);
      s += __shfl_xor(s, 32);
      if (t >= 125) s = -1e30f;
      float mw = s;
      mw = fmaxf(mw, __shfl_xor(mw, 1));
      mw = fmaxf(mw, __shfl_xor(mw, 2));
      mw = fmaxf(mw, __shfl_xor(mw, 4));
      mw = fmaxf(mw, __shfl_xor(mw, 8));
      float ev = __expf(s - mw);
      float sw = ev;
      sw += __shfl_xor(sw, 1);
      sw += __shfl_xor(sw, 2);
      sw += __shfl_xor(sw, 4);
      sw += __shfl_xor(sw, 8);
      if (lane < 16) scp[b * 128 + t] = f2h(ev);
      if (lane == 0) { red[b * 16 + wb * 2] = mw; red[b * 16 + wb * 2 + 1] = sw; }
    }
    __syncthreads();                                   // bar3
    // ---- P4: context from rowr (registers) x scp, window-scaled, shuffle-combined ----
    {
      float4 r01 = *(const float4*)&red[b * 16];
      float4 r23 = *(const float4*)&red[b * 16 + 4];
      float4 r45 = *(const float4*)&red[b * 16 + 8];
      float4 r67 = *(const float4*)&red[b * 16 + 12];
      float M = fmaxf(fmaxf(fmaxf(r01.x, r01.z), fmaxf(r23.x, r23.z)),
                      fmaxf(fmaxf(r45.x, r45.z), fmaxf(r67.x, r67.z)));
      float f0 = __expf(r01.x - M), f1 = __expf(r01.z - M);
      float f2 = __expf(r23.x - M), f3 = __expf(r23.z - M);
      float f4 = __expf(r45.x - M), f5 = __expf(r45.z - M);
      float f6 = __expf(r67.x - M), f7 = __expf(r67.z - M);
      float inv = 1.f / (f0*r01.y + f1*r01.w + f2*r23.y + f3*r23.w +
                         f4*r45.y + f5*r45.w + f6*r67.y + f7*r67.w);
      float fa, fb;
      if (q == 0)      { fa = f0; fb = f1; }
      else if (q == 1) { fa = f2; fb = f3; }
      else if (q == 2) { fa = f4; fb = f5; }
      else             { fa = f6; fb = f7; }
      float ca = 0.f, cb = 0.f;
      uint4 sA = *(const uint4*)(scp4 + b * 64 + q * 16);
      uint4 sB = *(const uint4*)(scp4 + b * 64 + q * 16 + 4);
      uint4 sC = *(const uint4*)(scp4 + b * 64 + q * 16 + 8);
      uint4 sD = *(const uint4*)(scp4 + b * 64 + q * 16 + 12);
      ca = dot2h(rowr[0], sA.x, ca); ca = dot2h(rowr[1], sA.y, ca);
      ca = dot2h(rowr[2], sA.z, ca); ca = dot2h(rowr[3], sA.w, ca);
      ca = dot2h(rowr[4], sB.x, ca); ca = dot2h(rowr[5], sB.y, ca);
      ca = dot2h(rowr[6], sB.z, ca); ca = dot2h(rowr[7], sB.w, ca);
      cb = dot2h(rowr[8], sC.x, cb); cb = dot2h(rowr[9], sC.y, cb);
      cb = dot2h(rowr[10], sC.z, cb); cb = dot2h(rowr[11], sC.w, cb);
      cb = dot2h(rowr[12], sD.x, cb); cb = dot2h(rowr[13], sD.y, cb);
      cb = dot2h(rowr[14], sD.z, cb); cb = dot2h(rowr[15], sD.w, cb);
      float part = ca * fa + cb * fb;
      part += __shfl_xor(part, 16);
      part += __shfl_xor(part, 32);
      if (lane < 16) {
        float hxf = hgX[b * 128 + u] + part * inv;
        outb[((size_t)(bg * 128) + step) * 128 + u] = f2bf(hxf);
        hxT[b * 136 + u] = f2h(hxf);
        hxP[b * 128 + u] = hxf;
      }
    }
    __syncthreads();                                   // bar4
  }
}

// ---------------- host launch ----------------
extern "C" void kernel_launch(void* const* d_in, const int* in_sizes, int n_in,
                              void* d_out, int out_size, void* d_ws, size_t ws_size,
                              hipStream_t stream)
{
  const float* x        = (const float*)d_in[0];
  const int*   y        = (const int*)d_in[1];
  const float* conv1_w  = (const float*)d_in[2];
  const float* conv1_b  = (const float*)d_in[3];
  const float* conv2_w  = (const float*)d_in[4];
  const float* conv2_b  = (const float*)d_in[5];
  const float* rnn_w_ih = (const float*)d_in[6];
  const float* rnn_w_hh = (const float*)d_in[7];
  const float* rnn_b_ih = (const float*)d_in[8];
  const float* rnn_b_hh = (const float*)d_in[9];
  const float* emb      = (const float*)d_in[10];
  const float* dec_w_ih = (const float*)d_in[11];
  const float* dec_w_hh = (const float*)d_in[12];
  const float* dec_b_ih = (const float*)d_in[13];
  const float* dec_b_hh = (const float*)d_in[14];
  const float* fc_w     = (const float*)d_in[15];
  const float* fc_b     = (const float*)d_in[16];
  const float* h_init   = (const float*)d_in[17];
  float* logits = (float*)d_out;

  char* ws = (char*)d_ws;
  size_t off = 0;
  auto alloc = [&](size_t bytes) { char* p = ws + off; off = (off + bytes + 255) & ~(size_t)255; return p; };
  u16* in1b  = (u16*)alloc(37453824);  // conv1 out bf16 (32,32,254,72pad)
  u16* hbf   = (u16*)alloc(4352000);   // h bf16 (4000,544)
  float* xge = (float*)alloc(6144000); // enc xg (4000,384)
  u32* ehb_k = (u32*)alloc(1024000);   // eh f16 k-pairs (32,64,125)
  u32* ehb_t = (u32*)alloc(1048576);   // eh f16 t-rows (32,128,64) u32
  float* xgd = (float*)alloc(6242304); // dec xg (4064,384)
  u16* adec  = (u16*)alloc(260096);    // emb gather (4064,32)
  u16* outb  = (u16*)alloc(1048576);   // decoder out bf16 (4096,128)
  u32* wT2e  = (u32*)alloc(98304);
  u32* wT2d  = (u32*)alloc(98304);
  u16* w1b   = (u16*)alloc(10240);
  u16* w2b   = (u16*)alloc(327680);
  u16* wihb  = (u16*)alloc(417792);
  u16* dwihb = (u16*)alloc(24576);
  u16* fcwb  = (u16*)alloc(1048576);

  hipFuncSetAttribute((const void*)conv2_k, hipFuncAttributeMaxDynamicSharedMemorySize, 153088);
  hipFuncSetAttribute((const void*)dec_k,   hipFuncAttributeMaxDynamicSharedMemorySize, 75136);

  prep_k<<<4272, 256, 0, stream>>>(rnn_w_hh, dec_w_hh, conv1_w, conv2_w, rnn_w_ih,
                                   dec_w_ih, fc_w, emb, y,
                                   wT2e, wT2d, w1b, w2b, wihb, dwihb, fcwb, adec);
  conv1_k<<<512, 256, 0, stream>>>(x, w1b, conv1_b, in1b);
  conv2_k<<<512, 256, 153088, stream>>>(in1b, w2b, conv2_b, hbf);
  gemm_k<<<dim3(63, 6), 256, 0, stream>>>(hbf, wihb, rnn_b_ih, xge, 4000, 384, 544);
  gemm_k<<<dim3(64, 6), 256, 0, stream>>>(adec, dwihb, dec_b_ih, xgd, 4064, 384, 32);
  enc_k<<<4, 1024, 0, stream>>>(wT2e, xge, rnn_b_hh, (u16*)ehb_k, (u16*)ehb_t);
  dec_k<<<16, 1024, 75136, stream>>>(wT2d, ehb_k, ehb_t, xgd, dec_b_hh, h_init, outb);
  gemm_k<<<dim3(64, 64), 256, 0, stream>>>(outb, fcwb, fc_b, logits, 4096, 4096, 128);
}